// Round 6
// baseline (113.264 us; speedup 1.0000x reference)
//
#include <hip/hip_runtime.h>

#define B_    16
#define CIN_  128
#define COUT_ 128
#define N_    4096
#define K_    16

typedef __attribute__((ext_vector_type(8))) _Float16 f16x8;   // 8 f16 = 4 VGPR
typedef __attribute__((ext_vector_type(2))) _Float16 f16x2;   // arithmetic type
typedef __attribute__((ext_vector_type(2))) __fp16   h16x2;   // pkrtz ret type
typedef __attribute__((ext_vector_type(4))) float f32x4;
typedef __attribute__((ext_vector_type(4))) int   i32x4;

// v_cvt_pkrtz_f16_f32 returns __fp16x2; bitcast to the _Float16x2 we compute in
__device__ inline f16x2 pkrtz(float a, float b) {
  union { h16x2 r; f16x2 f; } u;
  u.r = __builtin_amdgcn_cvt_pkrtz(a, b);
  return u.f;
}
__device__ inline unsigned h2u(f16x2 h) {          // bitcast half2 -> u32
  union { f16x2 h; unsigned u; } x; x.h = h; return x.u;
}
__device__ inline f16x2 u2h(unsigned u) {          // bitcast u32 -> half2
  union { unsigned u; f16x2 h; } x; x.u = u; return x.h;
}
__device__ inline unsigned short f2h(float f) {    // 1x v_cvt_f16_f32 (RNE)
  _Float16 h = (_Float16)f;
  union { _Float16 h; unsigned short u; } x; x.h = h; return x.u;
}

// ---------------------------------------------------------------------------
// R6 = R5 with the type fix (pkrtz wrapper bitcasts __fp16x2 -> _Float16x2;
// the MFMA f16 builtin accepted _Float16x8 operands already).
// Rationale: dur_us = ws-poison fill (~44us, fixed) + harness (~30us, fixed)
// + kernels (~38.5us). Kernel VALU is dominated by format shuffling: software
// f2bf (~4 ops/elt) in gemm, shift/and unpack + scalar adds (16 ops/16B) in
// aggr. f16 end-to-end gives hw packed cvt (1 op/2 elts), same-rate
// mfma_f32_16x16x32_f16, and packed f16 accumulate (v_pk_add_f16, 4 ops/16B).
// Accuracy improves: old absmax 2^-7 was exactly the bf16-storage ulp of h;
// f16 has 4 more mantissa bits; h in [0,~20] is far inside f16 range; f16 add
// error over 17 non-negative terms ~0.002 after /17.
//
// XCD-affinity (proven config): round-robin dispatch pins batch b to XCD b>>1
// in BOTH kernels -> aggr gathers hit the L2 that gemm filled.
// ---------------------------------------------------------------------------
// Kernel 1: h[b][n][co] = f16(relu(sum_ci W[co][ci]*x[b][ci][n]))
// 256 blocks x 1024 thr (1 block/CU, 16 waves); tile 256n x 128co.
// ---------------------------------------------------------------------------
__global__ __launch_bounds__(1024, 4) void gemm_relu_k(
    const float* __restrict__ W, const float* __restrict__ x,
    unsigned short* __restrict__ h) {
  __shared__ unsigned short Wl[128 * 136];   // [co][ci] f16, +8 pad (34.8 KB)
  __shared__ unsigned short He[256 * 144];   // [n][co] f16, +16 pad (73.7 KB)
  const int tid  = threadIdx.x;
  const int l    = blockIdx.x;          // 0..255
  const int slot = l >> 3;              // 0..31
  const int b    = ((l & 7) << 1) | (slot >> 4);
  const int n0   = (slot & 15) * 256;

  // ---- stage W fp32 -> f16 -> LDS: 4x v_cvt_pkrtz per 8 floats ----
#pragma unroll
  for (int r = 0; r < 2; ++r) {
    int id  = tid + 1024 * r;   // 0..2047 segments of 8 floats
    int co  = id >> 4;          // 0..127
    int seg = id & 15;          // 8-elt segment along ci
    const float4* wp = reinterpret_cast<const float4*>(W + co * CIN_ + 8 * seg);
    float4 v0 = wp[0];
    float4 v1 = wp[1];
    f16x2 q0 = pkrtz(v0.x, v0.y);
    f16x2 q1 = pkrtz(v0.z, v0.w);
    f16x2 q2 = pkrtz(v1.x, v1.y);
    f16x2 q3 = pkrtz(v1.z, v1.w);
    *reinterpret_cast<uint4*>(&Wl[co * 136 + 8 * seg]) =
        make_uint4(h2u(q0), h2u(q1), h2u(q2), h2u(q3));
  }

  const int lane = tid & 63;
  const int w    = tid >> 6;    // wave 0..15 -> n slice [n0+16w, +16)
  const int m    = lane & 15;
  const int quad = lane >> 4;

  // ---- A-fragments straight from global (overlap the W staging above);
  //      packed f16 conversion: 4x pkrtz per 8 loads ----
  const float* xb = x + (size_t)b * CIN_ * N_ + n0 + 16 * w + m;
  f16x8 a[4];
#pragma unroll
  for (int s = 0; s < 4; ++s)
#pragma unroll
    for (int jj = 0; jj < 4; ++jj) {
      float e0 = xb[(size_t)(32 * s + 8 * quad + 2 * jj)     * N_];
      float e1 = xb[(size_t)(32 * s + 8 * quad + 2 * jj + 1) * N_];
      f16x2 p = pkrtz(e0, e1);
      a[s][2 * jj]     = p[0];
      a[s][2 * jj + 1] = p[1];
    }

  __syncthreads();

  const int nrow = 16 * w + 4 * quad;   // block-local n of c[0]
#pragma unroll
  for (int t = 0; t < 8; ++t) {   // 8 co-tiles of 16
    f32x4 c = {0.f, 0.f, 0.f, 0.f};
#pragma unroll
    for (int s = 0; s < 4; ++s) { // K = 4 x 32
      f16x8 bf = *reinterpret_cast<const f16x8*>(
          &Wl[(16 * t + m) * 136 + 32 * s + 8 * quad]);
      c = __builtin_amdgcn_mfma_f32_16x16x32_f16(a[s], bf, c, 0, 0, 0);
    }
    int co = 16 * t + m;
#pragma unroll
    for (int r = 0; r < 4; ++r) {
      float v = c[r] > 0.f ? c[r] : 0.f;  // ReLU
      He[(nrow + r) * 144 + co] = f2h(v);  // 1 cvt; pad 144: distinct banks
    }
  }
  __syncthreads();

  // ---- vectorized store: 4 x dwordx4/thread, 1 KB contiguous per wave ----
  unsigned short* hb = h + ((size_t)b * N_ + n0) * COUT_;
  const int seg = tid & 15;
  const int nr  = tid >> 4;   // 0..63
#pragma unroll
  for (int p = 0; p < 4; ++p) {
    int n = nr + 64 * p;
    uint4 v = *reinterpret_cast<const uint4*>(&He[n * 144 + 8 * seg]);
    *reinterpret_cast<uint4*>(hb + (size_t)n * COUT_ + 8 * seg) = v;
  }
}

// ---------------------------------------------------------------------------
// Kernel 2: out[b][co][n] = (sum_{17} h[b][idx'][:])/17 + bias, idx' incl self
// Proven R0 shape: 1024 blocks x 256 thr; 64n x 128co tile; q=tid&15 -> 8 co,
// g=tid>>4 -> 4 n; unroll-2 over k. NEW: packed f16 accumulate (v_pk_add_f16)
// -- 4 VALU per gathered uint4 instead of 16 -- f32 unpack once in epilogue.
// ---------------------------------------------------------------------------
__global__ __launch_bounds__(256, 4) void aggr_k(
    const unsigned short* __restrict__ h, const int* __restrict__ ei,
    const float* __restrict__ bias, float* __restrict__ out) {
  __shared__ int idx_t[17 * 64];  // [k][n], k=16 is the self loop
  const int tid  = threadIdx.x;
  const int l    = blockIdx.x;
  const int rest = l >> 3;                        // 0..127
  const int b    = ((l & 7) << 1) | (rest >> 6);
  const int n0   = (rest & 63) * 64;

  {  // stage+transpose neighbor indices (coalesced int4, NT to spare L2)
    int n  = tid >> 2;       // 0..63
    int kq = tid & 3;        // int4 along k
    i32x4 v = __builtin_nontemporal_load(
        reinterpret_cast<const i32x4*>(ei + ((size_t)b * N_ + n0 + n) * K_) + kq);
    idx_t[(4 * kq + 0) * 64 + n] = v.x;
    idx_t[(4 * kq + 1) * 64 + n] = v.y;
    idx_t[(4 * kq + 2) * 64 + n] = v.z;
    idx_t[(4 * kq + 3) * 64 + n] = v.w;
    if (tid < 64) idx_t[16 * 64 + tid] = n0 + tid;  // self loop
  }
  __syncthreads();

  const int q = tid & 15;   // co = 8q..8q+7
  const int g = tid >> 4;   // n_local = 4g .. 4g+3
  const unsigned short* hb = h + (size_t)b * N_ * COUT_;

  // packed f16 accumulators: [n_local][dword pair of co]; f16 is safe here:
  // terms are non-negative, sums <~20 (far inside f16 range), ulp(20)=0.016,
  // 17 adds -> ~0.03 worst-case pre-norm, ~0.002 after /17.
  f16x2 acc2[4][4];
#pragma unroll
  for (int j = 0; j < 4; ++j)
#pragma unroll
    for (int d = 0; d < 4; ++d) acc2[j][d] = (f16x2)(_Float16)0;

#pragma unroll 2
  for (int k = 0; k < 17; ++k) {
    uint4 v[4];
#pragma unroll
    for (int j = 0; j < 4; ++j) {
      int node = idx_t[k * 64 + 4 * g + j];
      v[j] = *reinterpret_cast<const uint4*>(hb + (size_t)node * COUT_ + 8 * q);
    }
#pragma unroll
    for (int j = 0; j < 4; ++j) {   // 4x v_pk_add_f16 per uint4
      acc2[j][0] += u2h(v[j].x);
      acc2[j][1] += u2h(v[j].y);
      acc2[j][2] += u2h(v[j].z);
      acc2[j][3] += u2h(v[j].w);
    }
  }

  const float norm = 1.0f / 17.0f;
  const float4 bv0 = *reinterpret_cast<const float4*>(bias + 8 * q);
  const float4 bv1 = *reinterpret_cast<const float4*>(bias + 8 * q + 4);
  float* ob = out + (size_t)b * COUT_ * N_ + n0 + 4 * g;
#pragma unroll
  for (int c = 0; c < 8; ++c) {
    int co = 8 * q + c;
    float bb = (c < 4) ? ((c == 0) ? bv0.x : (c == 1) ? bv0.y : (c == 2) ? bv0.z : bv0.w)
                       : ((c == 4) ? bv1.x : (c == 5) ? bv1.y : (c == 6) ? bv1.z : bv1.w);
    float4 r;
    r.x = (float)acc2[0][c >> 1][c & 1] * norm + bb;
    r.y = (float)acc2[1][c >> 1][c & 1] * norm + bb;
    r.z = (float)acc2[2][c >> 1][c & 1] * norm + bb;
    r.w = (float)acc2[3][c >> 1][c & 1] * norm + bb;
    *reinterpret_cast<float4*>(ob + (size_t)co * N_) = r;  // 16B, 64B/segment
  }
}

extern "C" void kernel_launch(void* const* d_in, const int* in_sizes, int n_in,
                              void* d_out, int out_size, void* d_ws, size_t ws_size,
                              hipStream_t stream) {
  const float* x    = (const float*)d_in[0];
  const int*   ei   = (const int*)d_in[1];   // [2][B][N][K]; plane 0
  const float* W    = (const float*)d_in[2];
  const float* bias = (const float*)d_in[3];
  float* out = (float*)d_out;
  unsigned short* h = (unsigned short*)d_ws;  // 16 MB (f16 now)

  gemm_relu_k<<<dim3(256), dim3(1024), 0, stream>>>(W, x, h);
  aggr_k<<<dim3(B_ * N_ / 64), 256, 0, stream>>>(h, ei, bias, out);
}